// Round 16
// baseline (250.056 us; speedup 1.0000x reference)
//
#include <hip/hip_runtime.h>

// CNF forward: 8 fixed dopri5 steps x 6 stages, rows independent.
// R21 = R20/R17 (212us steady, best verified) + two barrier-overlap moves
// that add no register state:
//  * PRE-BARRIER OWN-J MM2: wave Q's MM1 writes h for j in [64Q,64Q+64) =
//    exactly MM2 chunks 2Q,2Q+1. Reading back its OWN writes needs only
//    lgkmcnt, not a barrier -> those 4 of 16 MM2 MFMAs + 4 sH reads issue
//    BEFORE barrier2, filling the convergence window; post-barrier chain
//    shrinks 25%. Runtime-chunk-index scratch (rule #20) avoided by
//    ROTATING w2f at load: w2f[m] = chunk (2*wave+m)&7, so register
//    indices stay literal; rotation lives in LDS addressing (cofs[m]).
//    fa accumulation order changes per wave = f32 reassociation only.
//  * 48-row bias table sBWT[48][256] (49KB, immutable): removes the
//    per-stage sBW fma+ds_write and its RAW-through-barrier1; bias read
//    shared between tiles A/B (8 -> 4 reads/stage). LDS 72.2KB -> still
//    2 blocks/CU (VGPR-bound).
// Tripwire: FETCH > 100 MB = spill -> revert to R20.

typedef __bf16 bf16x8 __attribute__((ext_vector_type(8)));
typedef __bf16 bf16x4 __attribute__((ext_vector_type(4)));
typedef float  f32x4  __attribute__((ext_vector_type(4)));
typedef unsigned int u32;

#define MFMA16(a, b, c) __builtin_amdgcn_mfma_f32_16x16x32_bf16((a), (b), (c), 0, 0, 0)

#define SY_S 76    // sY row stride in bf16 (38 dwords == 6 mod 32)
#define SH_S 268   // sH row stride in bf16 (134 dwords == 6 mod 32)

__device__ __forceinline__ float fast_tanh2(float x2) {   // x2 = 2*log2e*x
    float e = __builtin_amdgcn_exp2f(x2);                 // e^(2x)
    return 1.0f - 2.0f * __builtin_amdgcn_rcpf(e + 1.0f);
}
__device__ __forceinline__ bf16x8 cvt8(f32x4 a, f32x4 b) {
    bf16x8 r;
#pragma unroll
    for (int i = 0; i < 4; ++i) { r[i] = (__bf16)a[i]; r[4 + i] = (__bf16)b[i]; }
    return r;
}

extern "C" __global__ void __launch_bounds__(256, 2)
cnf_kernel(const float* __restrict__ Yg, const float* __restrict__ Eg,
           const float* __restrict__ W1g, const float* __restrict__ b1g,
           const float* __restrict__ W2g, const float* __restrict__ b2g,
           float* __restrict__ Og)
{
    // ---- LDS (~72.2 KB; 2 blocks/CU at 2 waves/EU) ----
    __shared__ float sBWT[48 * 256];                // per-(step,stage) bias*2log2e (immutable)
    __shared__ __align__(16) __bf16 sYA[16 * SY_S], sYB[16 * SY_S];
    __shared__ __align__(16) __bf16 sHA[16 * SH_S], sHB[16 * SH_S];
    __shared__ float sRedSS[128], sRedLP[128];

    const int tid  = threadIdx.x;
    const int wave = tid >> 6;        // 0..3
    const int lane = tid & 63;
    const int quad = lane >> 4;
    const int l16  = lane & 15;
    const int colb = wave * 16;       // own output-col tile base
    const int jb   = wave * 64;       // own hidden-j base
    const int rowA = blockIdx.x * 32 + l16;   // tile A batch row
    const int rowB = rowA + 16;               // tile B batch row

    const float TS  = 2.885390081777927f;    // 2*log2(e)
    const float IVS = 0.346573590279973f;    // ln(2)/2 = 1/TS
    const float dt  = 0.125f;

    // ---------------- bias table (immutable after first barrier) ----------------
    {
        const float b1r  = b1g[tid] * TS;
        const float w1tr = W1g[64 * 256 + tid] * TS;
        const float ctis[6] = {0.f, 0.2f, 0.3f, 0.8f, 8.f/9.f, 1.f};
#pragma unroll
        for (int st = 0; st < 6; ++st)
#pragma unroll
            for (int step = 0; step < 8; ++step)
                sBWT[(step * 6 + st) * 256 + tid] =
                    b1r + (dt * ((float)step + ctis[st])) * w1tr;
    }

    // ---------------- e fragments (both tiles) ----------------
    bf16x8 aeA0, aeA1, aeB0, aeB1;
    {
        const float* eA = Eg + rowA * 64;
        const float* eB = Eg + rowB * 64;
        aeA0 = cvt8(*(const f32x4*)(eA + quad * 8),      *(const f32x4*)(eA + quad * 8 + 4));
        aeA1 = cvt8(*(const f32x4*)(eA + 32 + quad * 8), *(const f32x4*)(eA + 32 + quad * 8 + 4));
        aeB0 = cvt8(*(const f32x4*)(eB + quad * 8),      *(const f32x4*)(eB + quad * 8 + 4));
        aeB1 = cvt8(*(const f32x4*)(eB + 32 + quad * 8), *(const f32x4*)(eB + 32 + quad * 8 + 4));
    }

    // ---------------- W1 fragments, PRE-SCALED by TS (A-op: [m=j][k=d]) ----
    bf16x8 w1f[8];
#pragma unroll
    for (int t = 0; t < 4; ++t) {
#pragma unroll
        for (int h = 0; h < 2; ++h) {
            const float* src = W1g + (h * 32 + quad * 8) * 256 + jb + t * 16 + l16;
            bf16x8 f;
#pragma unroll
            for (int i = 0; i < 8; ++i) f[i] = (__bf16)(src[i * 256] * TS);
            w1f[t * 2 + h] = f;
        }
    }

    // ---------------- ghf per tile: (gh0 .* v) f32 * IVS (undo W1 scale) ----
    float ghfA[16], ghfB[16];
#pragma unroll
    for (int t = 0; t < 4; ++t) {
        const float* wr = W2g + (jb + t * 16 + l16) * 64;
        bf16x8 aw0 = cvt8(*(const f32x4*)(wr + quad * 8),      *(const f32x4*)(wr + quad * 8 + 4));
        bf16x8 aw1 = cvt8(*(const f32x4*)(wr + 32 + quad * 8), *(const f32x4*)(wr + 32 + quad * 8 + 4));
        f32x4 vA = {0.f,0.f,0.f,0.f}, vB = {0.f,0.f,0.f,0.f};
        f32x4 gA = {0.f,0.f,0.f,0.f}, gB = {0.f,0.f,0.f,0.f};
        vA = MFMA16(w1f[t * 2 + 0], aeA0, vA);  vA = MFMA16(w1f[t * 2 + 1], aeA1, vA);
        vB = MFMA16(w1f[t * 2 + 0], aeB0, vB);  vB = MFMA16(w1f[t * 2 + 1], aeB1, vB);
        gA = MFMA16(aw0, aeA0, gA);             gA = MFMA16(aw1, aeA1, gA);
        gB = MFMA16(aw0, aeB0, gB);             gB = MFMA16(aw1, aeB1, gB);
#pragma unroll
        for (int i = 0; i < 4; ++i) {
            ghfA[t * 4 + i] = gA[i] * vA[i] * IVS;
            ghfB[t * 4 + i] = gB[i] * vB[i] * IVS;
        }
    }

    // ---------------- W2^T fragments, ROTATED: w2f[m] = chunk (2*wave+m)&7 ----
    // (keeps all register indices literal; rotation lives in LDS addressing)
    bf16x8 w2f[8];
    int cofs[8];   // sH bf16 offset of chunk m's j-base
#pragma unroll
    for (int m = 0; m < 8; ++m) {
        const int c = (2 * wave + m) & 7;
        cofs[m] = c * 32;
        const float* src = W2g + (c * 32 + quad * 8) * 64 + colb + l16;
        bf16x8 f;
#pragma unroll
        for (int i = 0; i < 8; ++i) f[i] = (__bf16)src[i * 64];
        w2f[m] = f;
    }

    // ---------------- state (lane layout: batch=l16, d=colb+quad*4+rg) ----
    f32x4 zvA = *(const f32x4*)(Yg + rowA * 64 + colb + quad * 4);
    f32x4 zvB = *(const f32x4*)(Yg + rowB * 64 + colb + quad * 4);
    f32x4 bb2 = *(const f32x4*)(b2g + colb + quad * 4);

    float kfA[6][4], kfB[6][4];   // k_dz in raw f32
    float lppA = 0.f, lppB = 0.f;

#define S0X(arr, g) 0.f
#define S1X(arr, g) (0.2f*arr[0][g])
#define S2X(arr, g) (0.075f*arr[0][g] + 0.225f*arr[1][g])
#define S3X(arr, g) ((44.f/45.f)*arr[0][g] + (-56.f/15.f)*arr[1][g] + (32.f/9.f)*arr[2][g])
#define S4X(arr, g) ((19372.f/6561.f)*arr[0][g] + (-25360.f/2187.f)*arr[1][g] + \
                     (64448.f/6561.f)*arr[2][g] + (-212.f/729.f)*arr[3][g])
#define S5X(arr, g) ((9017.f/3168.f)*arr[0][g] + (-355.f/33.f)*arr[1][g] + \
                     (46732.f/5247.f)*arr[2][g] + (49.f/176.f)*arr[3][g] + \
                     (-5103.f/18656.f)*arr[4][g])
#define CBX(arr, g) ((35.f/384.f)*arr[0][g] + (500.f/1113.f)*arr[2][g] + \
                     (125.f/192.f)*arr[3][g] + (-2187.f/6784.f)*arr[4][g] + \
                     (11.f/84.f)*arr[5][g])

    // matmul-1 pair: shared bias read (bw) inits both tiles' accumulators
#define MM1P(t, DODV) { \
    f32x4 bw = *(const f32x4*)(bwR + jb + (t)*16 + quad * 4); \
    { f32x4 ua = bw; \
      ua = MFMA16(w1f[(t)*2 + 0], a10A, ua); \
      ua = MFMA16(w1f[(t)*2 + 1], a11A, ua); \
      float h0 = fast_tanh2(ua[0]), h1 = fast_tanh2(ua[1]); \
      float h2 = fast_tanh2(ua[2]), h3 = fast_tanh2(ua[3]); \
      if (DODV) { \
          dvA += ghfA[(t)*4 + 0] * (1.f - h0*h0); \
          dvA += ghfA[(t)*4 + 1] * (1.f - h1*h1); \
          dvA += ghfA[(t)*4 + 2] * (1.f - h2*h2); \
          dvA += ghfA[(t)*4 + 3] * (1.f - h3*h3); \
      } \
      bf16x4 hv; hv[0]=(__bf16)h0; hv[1]=(__bf16)h1; hv[2]=(__bf16)h2; hv[3]=(__bf16)h3; \
      *(bf16x4*)(sHA + l16 * SH_S + jb + (t)*16 + quad * 4) = hv; } \
    { f32x4 ua = bw; \
      ua = MFMA16(w1f[(t)*2 + 0], a10B, ua); \
      ua = MFMA16(w1f[(t)*2 + 1], a11B, ua); \
      float h0 = fast_tanh2(ua[0]), h1 = fast_tanh2(ua[1]); \
      float h2 = fast_tanh2(ua[2]), h3 = fast_tanh2(ua[3]); \
      if (DODV) { \
          dvB += ghfB[(t)*4 + 0] * (1.f - h0*h0); \
          dvB += ghfB[(t)*4 + 1] * (1.f - h1*h1); \
          dvB += ghfB[(t)*4 + 2] * (1.f - h2*h2); \
          dvB += ghfB[(t)*4 + 3] * (1.f - h3*h3); \
      } \
      bf16x4 hv; hv[0]=(__bf16)h0; hv[1]=(__bf16)h1; hv[2]=(__bf16)h2; hv[3]=(__bf16)h3; \
      *(bf16x4*)(sHB + l16 * SH_S + jb + (t)*16 + quad * 4) = hv; } }

    // MM2 chunk m (rotated): chunk (2*wave+m)&7; m=0,1 are the wave's OWN j
#define MM2C(S, m, acc) { \
    bf16x8 hf = *(const bf16x8*)(sH##S + l16 * SH_S + cofs[m] + quad * 8); \
    acc = MFMA16(w2f[m], hf, acc); }

#define STAGE(st, DTB, DODV, SX) { \
    { bf16x4 yv; \
      yv[0] = (__bf16)(zvA[0] + dt * (SX(kfA,0))); \
      yv[1] = (__bf16)(zvA[1] + dt * (SX(kfA,1))); \
      yv[2] = (__bf16)(zvA[2] + dt * (SX(kfA,2))); \
      yv[3] = (__bf16)(zvA[3] + dt * (SX(kfA,3))); \
      *(bf16x4*)(sYA + l16 * SY_S + colb + quad * 4) = yv; } \
    { bf16x4 yv; \
      yv[0] = (__bf16)(zvB[0] + dt * (SX(kfB,0))); \
      yv[1] = (__bf16)(zvB[1] + dt * (SX(kfB,1))); \
      yv[2] = (__bf16)(zvB[2] + dt * (SX(kfB,2))); \
      yv[3] = (__bf16)(zvB[3] + dt * (SX(kfB,3))); \
      *(bf16x4*)(sYB + l16 * SY_S + colb + quad * 4) = yv; } \
    __syncthreads();  /* barrier1: sY */ \
    const float* bwR = sBWT + (step * 6 + (st)) * 256; \
    bf16x8 a10A = *(const bf16x8*)(sYA + l16 * SY_S + quad * 8); \
    bf16x8 a11A = *(const bf16x8*)(sYA + l16 * SY_S + 32 + quad * 8); \
    bf16x8 a10B = *(const bf16x8*)(sYB + l16 * SY_S + quad * 8); \
    bf16x8 a11B = *(const bf16x8*)(sYB + l16 * SY_S + 32 + quad * 8); \
    float dvA = 0.f, dvB = 0.f; \
    MM1P(0, DODV) MM1P(1, DODV) MM1P(2, DODV) MM1P(3, DODV) \
    /* own-j MM2 pre-barrier: chunks m=0,1 read THIS wave's sH writes */ \
    f32x4 faA0 = bb2, faA1 = {0.f,0.f,0.f,0.f}; \
    f32x4 faB0 = bb2, faB1 = {0.f,0.f,0.f,0.f}; \
    MM2C(A,0,faA0) MM2C(B,0,faB0) MM2C(A,1,faA1) MM2C(B,1,faB1) \
    __syncthreads();  /* barrier2: all sH */ \
    MM2C(A,2,faA0) MM2C(B,2,faB0) MM2C(A,3,faA1) MM2C(B,3,faB1) \
    MM2C(A,4,faA0) MM2C(B,4,faB0) MM2C(A,5,faA1) MM2C(B,5,faB1) \
    MM2C(A,6,faA0) MM2C(B,6,faB0) MM2C(A,7,faA1) MM2C(B,7,faB1) \
    f32x4 faA = faA0 + faA1, faB = faB0 + faB1; \
    kfA[st][0] = faA[0]; kfA[st][1] = faA[1]; kfA[st][2] = faA[2]; kfA[st][3] = faA[3]; \
    kfB[st][0] = faB[0]; kfB[st][1] = faB[1]; kfB[st][2] = faB[2]; kfB[st][3] = faB[3]; \
    if (DODV) { lppA -= (DTB) * dvA; lppB -= (DTB) * dvB; } }

    for (int step = 0; step < 8; ++step) {
        STAGE(0, dt*(35.f/384.f),    1, S0X)
        STAGE(1, 0.f,                0, S1X)
        STAGE(2, dt*(500.f/1113.f),  1, S2X)
        STAGE(3, dt*(125.f/192.f),   1, S3X)
        STAGE(4, dt*(-2187.f/6784.f),1, S4X)
        STAGE(5, dt*(11.f/84.f),     1, S5X)
        zvA[0] += dt * CBX(kfA,0);  zvA[1] += dt * CBX(kfA,1);
        zvA[2] += dt * CBX(kfA,2);  zvA[3] += dt * CBX(kfA,3);
        zvB[0] += dt * CBX(kfB,0);  zvB[1] += dt * CBX(kfB,1);
        zvB[2] += dt * CBX(kfB,2);  zvB[3] += dt * CBX(kfB,3);
    }

    // ---------------- epilogue ----------------
    *(f32x4*)(Og + rowA * 64 + colb + quad * 4) = zvA;
    *(f32x4*)(Og + rowB * 64 + colb + quad * 4) = zvB;
    float ssA = zvA[0]*zvA[0] + zvA[1]*zvA[1] + zvA[2]*zvA[2] + zvA[3]*zvA[3];
    float ssB = zvB[0]*zvB[0] + zvB[1]*zvB[1] + zvB[2]*zvB[2] + zvB[3]*zvB[3];
    ssA += __shfl_xor(ssA, 16);  ssA += __shfl_xor(ssA, 32);
    ssB += __shfl_xor(ssB, 16);  ssB += __shfl_xor(ssB, 32);
    float lpA = lppA;  lpA += __shfl_xor(lpA, 16);  lpA += __shfl_xor(lpA, 32);
    float lpB = lppB;  lpB += __shfl_xor(lpB, 16);  lpB += __shfl_xor(lpB, 32);
    if (quad == 0) {
        sRedSS[wave * 16 + l16] = ssA;       sRedLP[wave * 16 + l16] = lpA;
        sRedSS[64 + wave * 16 + l16] = ssB;  sRedLP[64 + wave * 16 + l16] = lpB;
    }
    __syncthreads();
    if (tid < 32) {
        const float CLOG = -58.8120661f;  // -32*ln(2*pi)
        int half = tid >> 4, r = tid & 15, base = half * 64;
        float sfull = sRedSS[base + r] + sRedSS[base + 16 + r]
                    + sRedSS[base + 32 + r] + sRedSS[base + 48 + r];
        float lfull = sRedLP[base + r] + sRedLP[base + 16 + r]
                    + sRedLP[base + 32 + r] + sRedLP[base + 48 + r];
        Og[32768 * 64 + blockIdx.x * 32 + half * 16 + r] = CLOG - 0.5f * sfull - lfull;
    }
}

extern "C" void kernel_launch(void* const* d_in, const int* in_sizes, int n_in,
                              void* d_out, int out_size, void* d_ws, size_t ws_size,
                              hipStream_t stream) {
    const float* Yg  = (const float*)d_in[0];
    const float* Eg  = (const float*)d_in[1];
    const float* W1g = (const float*)d_in[2];  // [65][256]
    const float* b1g = (const float*)d_in[3];
    const float* W2g = (const float*)d_in[4];  // [256][64]
    const float* b2g = (const float*)d_in[5];
    float* Og = (float*)d_out;                 // z (32768*64) then log_px (32768)
    cnf_kernel<<<dim3(1024), dim3(256), 0, stream>>>(Yg, Eg, W1g, b1g, W2g, b2g, Og);
}